// Round 9
// baseline (113.777 us; speedup 1.0000x reference)
//
#include <hip/hip_runtime.h>
#include <hip/hip_bf16.h>

#define SCOPE 63
#define BLOCK_THREADS 64
#define ROWS_PER_BLOCK 64
#define TILE_ELEMS (ROWS_PER_BLOCK * SCOPE)   // 4032 floats = 16128 B

// ---------------------------------------------------------------------------
// Kernel 1: inverse filter g = IFFT( 1 / FFT(delta - f) ) in fp64. Negligible.
// ---------------------------------------------------------------------------
__global__ void compute_inverse_filter(const float* __restrict__ f,
                                       float* __restrict__ g) {
    __shared__ double hre[SCOPE];
    __shared__ double him[SCOPE];
    const double TWO_PI = 6.283185307179586476925286766559;
    int t = threadIdx.x;
    if (t < SCOPE) {
        double re = 0.0, im = 0.0;
        for (int n = 0; n < SCOPE; ++n) {
            double x = (n == 0 ? 1.0 : 0.0) - (double)f[n];
            double ang = -TWO_PI * (double)(t * n) / (double)SCOPE;
            re += x * cos(ang);
            im += x * sin(ang);
        }
        double d = re * re + im * im;
        hre[t] = re / d;
        him[t] = -im / d;
    }
    __syncthreads();
    if (t < SCOPE) {
        double acc = 0.0;
        for (int k = 0; k < SCOPE; ++k) {
            double ang = TWO_PI * (double)(k * t) / (double)SCOPE;
            acc += hre[k] * cos(ang) - him[k] * sin(ang);
        }
        g[t] = (float)(acc / (double)SCOPE);
    }
}

// ---------------------------------------------------------------------------
// Compile-time-unrolled helpers (static indices only -> SROA to registers).
// ---------------------------------------------------------------------------
template <int J>
struct LoadArr {
    __device__ static inline void run(float (&d)[SCOPE], const float* s) {
        LoadArr<J - 1>::run(d, s);
        d[J] = s[J];
    }
};
template <>
struct LoadArr<-1> {
    __device__ static inline void run(float (&)[SCOPE], const float*) {}
};

// Wave-uniform load forced into SGPRs: v_fmac can read 1 SGPR operand free,
// and this removes 63 VGPRs from the live set.
template <int J>
struct LoadUniformArr {
    __device__ static inline void run(float (&d)[SCOPE], const float* s) {
        LoadUniformArr<J - 1>::run(d, s);
        d[J] = __uint_as_float(__builtin_amdgcn_readfirstlane(__float_as_uint(s[J])));
    }
};
template <>
struct LoadUniformArr<-1> {
    __device__ static inline void run(float (&)[SCOPE], const float*) {}
};

template <int J>
struct StoreArr {
    __device__ static inline void run(float* d, const float (&s)[SCOPE]) {
        StoreArr<J - 1>::run(d, s);
        d[J] = s[J];
    }
};
template <>
struct StoreArr<-1> {
    __device__ static inline void run(float*, const float (&)[SCOPE]) {}
};

// acc[n] = g[0] * a[n]   (m = 0 initialization)
template <int N>
struct InitAcc {
    __device__ static inline void run(float (&acc)[SCOPE], const float (&a)[SCOPE],
                                      const float (&g)[SCOPE]) {
        InitAcc<N - 1>::run(acc, a, g);
        acc[N] = g[0] * a[N];
    }
};
template <>
struct InitAcc<-1> {
    __device__ static inline void run(float (&)[SCOPE], const float (&)[SCOPE],
                                      const float (&)[SCOPE]) {}
};

// For fixed M: acc[n] += g[M] * a[(n - M) mod 63], all n  (63 independent FMAs
// -> dependency distance 63 between reuses of the same acc[n]: full ILP)
template <int M, int N>
struct ConvRow {
    __device__ static inline void run(float (&acc)[SCOPE], const float (&a)[SCOPE],
                                      const float (&g)[SCOPE]) {
        ConvRow<M, N - 1>::run(acc, a, g);
        acc[N] += g[M] * a[(N - M + SCOPE) % SCOPE];
    }
};
template <int M>
struct ConvRow<M, -1> {
    __device__ static inline void run(float (&)[SCOPE], const float (&)[SCOPE],
                                      const float (&)[SCOPE]) {}
};

template <int M>
struct ConvOuter {
    __device__ static inline void run(float (&acc)[SCOPE], const float (&a)[SCOPE],
                                      const float (&g)[SCOPE]) {
        ConvOuter<M - 1>::run(acc, a, g);
        ConvRow<M, SCOPE - 1>::run(acc, a, g);
    }
};
template <>
struct ConvOuter<0> {
    __device__ static inline void run(float (&acc)[SCOPE], const float (&a)[SCOPE],
                                      const float (&g)[SCOPE]) {
        InitAcc<SCOPE - 1>::run(acc, a, g);
    }
};

// ---------------------------------------------------------------------------
// Kernel 2: per-row circular convolution. One wave per block, 64 rows/block.
// m-outer register accumulation; no barrier while acc[] is live.
// amdgpu_waves_per_eu(2,2): occupancy is LDS-capped at ~2.5 waves/EU anyway,
// so cap the scheduler's occupancy target at 2 -> regalloc may use up to 256
// VGPRs and keep the ILP-rich m-outer schedule instead of re-serializing.
// ---------------------------------------------------------------------------
__global__ void __launch_bounds__(BLOCK_THREADS)
__attribute__((amdgpu_waves_per_eu(2, 2)))
circ_conv_kernel(const float* __restrict__ A,
                 const float* __restrict__ G,
                 float* __restrict__ O) {
    __shared__ __align__(16) float tile[TILE_ELEMS];

    const int lane = threadIdx.x;   // 1 wave per block

    const long long row0 = (long long)blockIdx.x * ROWS_PER_BLOCK;
    const float* __restrict__ src = A + row0 * SCOPE;
    float* __restrict__ dst       = O + row0 * SCOPE;

    // ---- filter into SGPRs (wave-uniform) ----
    float g[SCOPE];
    LoadUniformArr<SCOPE - 1>::run(g, G);

    // ---- stage 64 rows (4032 floats) into LDS, coalesced ----
    const float4* src4 = (const float4*)src;
    float4* w4 = (float4*)tile;
#pragma unroll
    for (int it = 0; it < 15; ++it)
        w4[it * 64 + lane] = src4[it * 64 + lane];
#pragma unroll
    for (int it = 0; it < 3; ++it)
        tile[3840 + it * 64 + lane] = src[3840 + it * 64 + lane];

    __syncthreads();   // single wave: compiles to waitcnt only

    // ---- lane's own row (LDS stride 63 floats: 2-way bank alias = free) ----
    float a[SCOPE];
    float* myrow = tile + lane * SCOPE;
    LoadArr<SCOPE - 1>::run(a, myrow);

    // ---- m-outer circular convolution, acc[] fully in registers ----
    float acc[SCOPE];
    ConvOuter<SCOPE - 1>::run(acc, a, g);

    // ---- write results to own LDS row (lane-private; no barrier needed) ----
    StoreArr<SCOPE - 1>::run(myrow, acc);

    __syncthreads();

    // ---- coalesced store ----
    float4* dst4 = (float4*)dst;
#pragma unroll
    for (int it = 0; it < 15; ++it)
        dst4[it * 64 + lane] = w4[it * 64 + lane];
#pragma unroll
    for (int it = 0; it < 3; ++it)
        dst[3840 + it * 64 + lane] = tile[3840 + it * 64 + lane];
}

// ---------------------------------------------------------------------------
extern "C" void kernel_launch(void* const* d_in, const int* in_sizes, int n_in,
                              void* d_out, int out_size, void* d_ws, size_t ws_size,
                              hipStream_t stream) {
    const float* activations = (const float*)d_in[0];
    const float* filt        = (const float*)d_in[1];
    float* out               = (float*)d_out;
    float* g                 = (float*)d_ws;   // 63 floats of scratch

    hipLaunchKernelGGL(compute_inverse_filter, dim3(1), dim3(64), 0, stream,
                       filt, g);

    const long long total = (long long)in_sizes[0];
    const long long rows  = total / SCOPE;                 // 524288
    const int blocks      = (int)(rows / ROWS_PER_BLOCK);  // 8192, exact

    hipLaunchKernelGGL(circ_conv_kernel, dim3(blocks), dim3(BLOCK_THREADS), 0,
                       stream, activations, g, out);
}

// Round 10
// 102.929 us; speedup vs baseline: 1.1054x; 1.1054x over previous
//
#include <hip/hip_runtime.h>
#include <hip/hip_bf16.h>

#define SCOPE 63
#define BLOCK_THREADS 64
#define ROWS_PER_BLOCK 64
#define TILE_ELEMS (ROWS_PER_BLOCK * SCOPE)   // 4032 floats = 16128 B
#define CHUNK 21                              // 3 chunks of 21 accumulators

// ---------------------------------------------------------------------------
// Kernel 1: inverse filter g = IFFT( 1 / FFT(delta - f) ) in fp64. Negligible.
// ---------------------------------------------------------------------------
__global__ void compute_inverse_filter(const float* __restrict__ f,
                                       float* __restrict__ g) {
    __shared__ double hre[SCOPE];
    __shared__ double him[SCOPE];
    const double TWO_PI = 6.283185307179586476925286766559;
    int t = threadIdx.x;
    if (t < SCOPE) {
        double re = 0.0, im = 0.0;
        for (int n = 0; n < SCOPE; ++n) {
            double x = (n == 0 ? 1.0 : 0.0) - (double)f[n];
            double ang = -TWO_PI * (double)(t * n) / (double)SCOPE;
            re += x * cos(ang);
            im += x * sin(ang);
        }
        double d = re * re + im * im;
        hre[t] = re / d;
        him[t] = -im / d;
    }
    __syncthreads();
    if (t < SCOPE) {
        double acc = 0.0;
        for (int k = 0; k < SCOPE; ++k) {
            double ang = TWO_PI * (double)(k * t) / (double)SCOPE;
            acc += hre[k] * cos(ang) - him[k] * sin(ang);
        }
        g[t] = (float)(acc / (double)SCOPE);
    }
}

// ---------------------------------------------------------------------------
// Compile-time-unrolled helpers (static indices only -> SROA to registers).
// ---------------------------------------------------------------------------
template <int J>
struct LoadArr {
    __device__ static inline void run(float (&d)[SCOPE], const float* s) {
        LoadArr<J - 1>::run(d, s);
        d[J] = s[J];
    }
};
template <>
struct LoadArr<-1> {
    __device__ static inline void run(float (&)[SCOPE], const float*) {}
};

// FMA tap M applied to chunk [N0, N0+LEN): acc[i] += gm * a[(N0+i-M) mod 63]
template <int N0, int LEN, int M, int I>
struct TapRow {
    __device__ static inline void run(float (&acc)[LEN], const float (&a)[SCOPE],
                                      float gm) {
        TapRow<N0, LEN, M, I - 1>::run(acc, a, gm);
        acc[I] += gm * a[(N0 + I - M + SCOPE) % SCOPE];
    }
};
template <int N0, int LEN, int M>
struct TapRow<N0, LEN, M, -1> {
    __device__ static inline void run(float (&)[LEN], const float (&)[SCOPE], float) {}
};

// Loop over taps M = 0..62 for one chunk; g[M] is a uniform LDS broadcast read
// (all 63 reads within a chunk are independent -> compiler prefetches ahead).
template <int N0, int LEN, int M>
struct TapLoop {
    __device__ static inline void run(float (&acc)[LEN], const float (&a)[SCOPE],
                                      const float* gs) {
        TapLoop<N0, LEN, M - 1>::run(acc, a, gs);
        const float gm = gs[M];
        TapRow<N0, LEN, M, LEN - 1>::run(acc, a, gm);
    }
};
template <int N0, int LEN>
struct TapLoop<N0, LEN, 0> {   // M = 0 initializes the accumulators
    __device__ static inline void run(float (&acc)[LEN], const float (&a)[SCOPE],
                                      const float* gs) {
        const float g0 = gs[0];
#pragma unroll
        for (int i = 0; i < LEN; ++i) acc[i] = g0 * a[N0 + i];
    }
};

template <int N0, int LEN, int I>
struct StoreChunk {
    __device__ static inline void run(float* myrow, const float (&acc)[LEN]) {
        StoreChunk<N0, LEN, I - 1>::run(myrow, acc);
        myrow[N0 + I] = acc[I];
    }
};
template <int N0, int LEN>
struct StoreChunk<N0, LEN, -1> {
    __device__ static inline void run(float*, const float (&)[LEN]) {}
};

template <int N0, int LEN>
__device__ inline void do_chunk(float* myrow, const float (&a)[SCOPE],
                                const float* gs) {
    float acc[LEN];
    TapLoop<N0, LEN, SCOPE - 1>::run(acc, a, gs);
    StoreChunk<N0, LEN, LEN - 1>::run(myrow, acc);
}

// ---------------------------------------------------------------------------
// Kernel 2: per-row circular convolution. One wave per block, 64 rows/block.
// Working set sized for the compiler's 128-VGPR comfort zone:
//   a[63] + acc[21] + overhead ~= 100 regs -> no re-serialization, no spill.
// Chunks are separated by memory clobbers so the 3x63 g-reads cannot be CSE'd
// into 63 live registers (which would recreate the pressure squeeze).
// ---------------------------------------------------------------------------
__global__ void __launch_bounds__(BLOCK_THREADS)
circ_conv_kernel(const float* __restrict__ A,
                 const float* __restrict__ G,
                 float* __restrict__ O) {
    __shared__ __align__(16) float tile[TILE_ELEMS];
    __shared__ float gs[SCOPE];

    const int lane = threadIdx.x;   // 1 wave per block

    const long long row0 = (long long)blockIdx.x * ROWS_PER_BLOCK;
    const float* __restrict__ src = A + row0 * SCOPE;
    float* __restrict__ dst       = O + row0 * SCOPE;

    if (lane < SCOPE) gs[lane] = G[lane];

    // ---- stage 64 rows (4032 floats) into LDS, coalesced ----
    const float4* src4 = (const float4*)src;
    float4* w4 = (float4*)tile;
#pragma unroll
    for (int it = 0; it < 15; ++it)
        w4[it * 64 + lane] = src4[it * 64 + lane];
#pragma unroll
    for (int it = 0; it < 3; ++it)
        tile[3840 + it * 64 + lane] = src[3840 + it * 64 + lane];

    __syncthreads();   // single wave: compiles to waitcnt only

    // ---- lane's own row (LDS stride 63 floats: 2-way bank alias = free) ----
    float a[SCOPE];
    float* myrow = tile + lane * SCOPE;
    LoadArr<SCOPE - 1>::run(a, myrow);

    // ---- 3 chunks of 21 outputs; clobbers split g-read live ranges ----
    do_chunk<0, CHUNK>(myrow, a, gs);
    asm volatile("" ::: "memory");
    do_chunk<CHUNK, CHUNK>(myrow, a, gs);
    asm volatile("" ::: "memory");
    do_chunk<2 * CHUNK, CHUNK>(myrow, a, gs);

    __syncthreads();

    // ---- coalesced store ----
    float4* dst4 = (float4*)dst;
#pragma unroll
    for (int it = 0; it < 15; ++it)
        dst4[it * 64 + lane] = w4[it * 64 + lane];
#pragma unroll
    for (int it = 0; it < 3; ++it)
        dst[3840 + it * 64 + lane] = tile[3840 + it * 64 + lane];
}

// ---------------------------------------------------------------------------
extern "C" void kernel_launch(void* const* d_in, const int* in_sizes, int n_in,
                              void* d_out, int out_size, void* d_ws, size_t ws_size,
                              hipStream_t stream) {
    const float* activations = (const float*)d_in[0];
    const float* filt        = (const float*)d_in[1];
    float* out               = (float*)d_out;
    float* g                 = (float*)d_ws;   // 63 floats of scratch

    hipLaunchKernelGGL(compute_inverse_filter, dim3(1), dim3(64), 0, stream,
                       filt, g);

    const long long total = (long long)in_sizes[0];
    const long long rows  = total / SCOPE;                 // 524288
    const int blocks      = (int)(rows / ROWS_PER_BLOCK);  // 8192, exact

    hipLaunchKernelGGL(circ_conv_kernel, dim3(blocks), dim3(BLOCK_THREADS), 0,
                       stream, activations, g, out);
}

// Round 11
// 102.836 us; speedup vs baseline: 1.1064x; 1.0009x over previous
//
#include <hip/hip_runtime.h>
#include <hip/hip_bf16.h>

#define SCOPE 63
#define BLOCK_THREADS 64
#define ROWS_PER_BLOCK 64
#define TILE_ELEMS (ROWS_PER_BLOCK * SCOPE)   // 4032 floats = 16128 B
#define CHUNK 21                              // 3 chunks of 21 accumulators

// ---------------------------------------------------------------------------
// Kernel 1: inverse filter g = IFFT( 1 / FFT(delta - f) ) in fp64. Negligible.
// ---------------------------------------------------------------------------
__global__ void compute_inverse_filter(const float* __restrict__ f,
                                       float* __restrict__ g) {
    __shared__ double hre[SCOPE];
    __shared__ double him[SCOPE];
    const double TWO_PI = 6.283185307179586476925286766559;
    int t = threadIdx.x;
    if (t < SCOPE) {
        double re = 0.0, im = 0.0;
        for (int n = 0; n < SCOPE; ++n) {
            double x = (n == 0 ? 1.0 : 0.0) - (double)f[n];
            double ang = -TWO_PI * (double)(t * n) / (double)SCOPE;
            re += x * cos(ang);
            im += x * sin(ang);
        }
        double d = re * re + im * im;
        hre[t] = re / d;
        him[t] = -im / d;
    }
    __syncthreads();
    if (t < SCOPE) {
        double acc = 0.0;
        for (int k = 0; k < SCOPE; ++k) {
            double ang = TWO_PI * (double)(k * t) / (double)SCOPE;
            acc += hre[k] * cos(ang) - him[k] * sin(ang);
        }
        g[t] = (float)(acc / (double)SCOPE);
    }
}

// ---------------------------------------------------------------------------
// Compile-time-unrolled helpers (static indices only -> SROA to registers).
// ---------------------------------------------------------------------------
template <int J>
struct LoadArr {
    __device__ static inline void run(float (&d)[SCOPE], const float* s) {
        LoadArr<J - 1>::run(d, s);
        d[J] = s[J];
    }
};
template <>
struct LoadArr<-1> {
    __device__ static inline void run(float (&)[SCOPE], const float*) {}
};

// Load 9 consecutive g values (independent ds_reads, issued back-to-back).
template <int BASE, int J>
struct LoadG9r {
    __device__ static inline void run(float (&d)[9], const float* __restrict__ gs) {
        LoadG9r<BASE, J - 1>::run(d, gs);
        d[J] = gs[BASE + J];
    }
};
template <int BASE>
struct LoadG9r<BASE, -1> {
    __device__ static inline void run(float (&)[9], const float* __restrict__) {}
};
template <int BASE>
__device__ inline void LoadG9(float (&d)[9], const float* __restrict__ gs) {
    LoadG9r<BASE, 8>::run(d, gs);
}

// FMA tap M applied to chunk [N0, N0+LEN): acc[i] += gm * a[(N0+i-M) mod 63]
template <int N0, int LEN, int M, int I>
struct TapRow {
    __device__ static inline void run(float (&acc)[LEN], const float (&a)[SCOPE],
                                      float gm) {
        TapRow<N0, LEN, M, I - 1>::run(acc, a, gm);
        acc[I] += gm * a[(N0 + I - M + SCOPE) % SCOPE];
    }
};
template <int N0, int LEN, int M>
struct TapRow<N0, LEN, M, -1> {
    __device__ static inline void run(float (&)[LEN], const float (&)[SCOPE], float) {}
};

// One batch of 9 taps (M = BM..BM+8) from a register-resident g batch.
// INIT=true: tap BM (=0) initializes the accumulators instead of accumulating.
template <int N0, int LEN, int BM, int J, bool INIT>
struct Batch9 {
    __device__ static inline void run(float (&acc)[LEN], const float (&a)[SCOPE],
                                      const float (&g)[9]) {
        Batch9<N0, LEN, BM, J - 1, INIT>::run(acc, a, g);
        TapRow<N0, LEN, BM + J, LEN - 1>::run(acc, a, g[J]);
    }
};
template <int N0, int LEN, int BM, bool INIT>
struct Batch9<N0, LEN, BM, 0, INIT> {
    __device__ static inline void run(float (&acc)[LEN], const float (&a)[SCOPE],
                                      const float (&g)[9]) {
        if constexpr (INIT) {
#pragma unroll
            for (int i = 0; i < LEN; ++i) acc[i] = g[0] * a[N0 + i];
        } else {
            TapRow<N0, LEN, BM, LEN - 1>::run(acc, a, g[0]);
        }
    }
};

template <int N0, int LEN, int I>
struct StoreChunk {
    __device__ static inline void run(float* myrow, const float (&acc)[LEN]) {
        StoreChunk<N0, LEN, I - 1>::run(myrow, acc);
        myrow[N0 + I] = acc[I];
    }
};
template <int N0, int LEN>
struct StoreChunk<N0, LEN, -1> {
    __device__ static inline void run(float*, const float (&)[LEN]) {}
};

// One chunk of LEN outputs: 7 batches of 9 taps, g double-buffered through
// registers so the next batch's ds_reads are in flight under this batch's
// 9x21 FMAs (378 cyc cover >> ~120 cyc LDS latency).
template <int N0, int LEN>
__device__ inline void do_chunk(float* __restrict__ myrow,
                                const float (&a)[SCOPE],
                                const float* __restrict__ gs) {
    float acc[LEN];
    float gA[9], gB[9];
    LoadG9<0>(gA, gs);
    LoadG9<9>(gB, gs);
    Batch9<N0, LEN, 0, 8, true>::run(acc, a, gA);    // taps 0..8 (init)
    LoadG9<18>(gA, gs);
    Batch9<N0, LEN, 9, 8, false>::run(acc, a, gB);   // taps 9..17
    LoadG9<27>(gB, gs);
    Batch9<N0, LEN, 18, 8, false>::run(acc, a, gA);  // taps 18..26
    LoadG9<36>(gA, gs);
    Batch9<N0, LEN, 27, 8, false>::run(acc, a, gB);  // taps 27..35
    LoadG9<45>(gB, gs);
    Batch9<N0, LEN, 36, 8, false>::run(acc, a, gA);  // taps 36..44
    LoadG9<54>(gA, gs);
    Batch9<N0, LEN, 45, 8, false>::run(acc, a, gB);  // taps 45..53
    Batch9<N0, LEN, 54, 8, false>::run(acc, a, gA);  // taps 54..62
    StoreChunk<N0, LEN, LEN - 1>::run(myrow, acc);
}

// ---------------------------------------------------------------------------
// Kernel 2: per-row circular convolution. One wave per block, 64 rows/block.
// Working set: a[63] + acc[21] + gA[9] + gB[9] + overhead ~= 115 < 128 VGPR.
// Chunks separated by memory clobbers so the 3x63 g-reads cannot be CSE'd
// into 63 live registers (which would recreate the pressure squeeze).
// ---------------------------------------------------------------------------
__global__ void __launch_bounds__(BLOCK_THREADS)
circ_conv_kernel(const float* __restrict__ A,
                 const float* __restrict__ G,
                 float* __restrict__ O) {
    __shared__ __align__(16) float tile[TILE_ELEMS];
    __shared__ float gs[SCOPE];

    const int lane = threadIdx.x;   // 1 wave per block

    const long long row0 = (long long)blockIdx.x * ROWS_PER_BLOCK;
    const float* __restrict__ src = A + row0 * SCOPE;
    float* __restrict__ dst       = O + row0 * SCOPE;

    if (lane < SCOPE) gs[lane] = G[lane];

    // ---- stage 64 rows (4032 floats) into LDS, coalesced ----
    const float4* src4 = (const float4*)src;
    float4* w4 = (float4*)tile;
#pragma unroll
    for (int it = 0; it < 15; ++it)
        w4[it * 64 + lane] = src4[it * 64 + lane];
#pragma unroll
    for (int it = 0; it < 3; ++it)
        tile[3840 + it * 64 + lane] = src[3840 + it * 64 + lane];

    __syncthreads();   // single wave: compiles to waitcnt only

    // ---- lane's own row (LDS stride 63 floats: 2-way bank alias = free) ----
    float a[SCOPE];
    float* myrow = tile + lane * SCOPE;
    LoadArr<SCOPE - 1>::run(a, myrow);

    // ---- 3 chunks of 21 outputs; clobbers split g-read live ranges ----
    do_chunk<0, CHUNK>(myrow, a, gs);
    asm volatile("" ::: "memory");
    do_chunk<CHUNK, CHUNK>(myrow, a, gs);
    asm volatile("" ::: "memory");
    do_chunk<2 * CHUNK, CHUNK>(myrow, a, gs);

    __syncthreads();

    // ---- coalesced store ----
    float4* dst4 = (float4*)dst;
#pragma unroll
    for (int it = 0; it < 15; ++it)
        dst4[it * 64 + lane] = w4[it * 64 + lane];
#pragma unroll
    for (int it = 0; it < 3; ++it)
        dst[3840 + it * 64 + lane] = tile[3840 + it * 64 + lane];
}

// ---------------------------------------------------------------------------
extern "C" void kernel_launch(void* const* d_in, const int* in_sizes, int n_in,
                              void* d_out, int out_size, void* d_ws, size_t ws_size,
                              hipStream_t stream) {
    const float* activations = (const float*)d_in[0];
    const float* filt        = (const float*)d_in[1];
    float* out               = (float*)d_out;
    float* g                 = (float*)d_ws;   // 63 floats of scratch

    hipLaunchKernelGGL(compute_inverse_filter, dim3(1), dim3(64), 0, stream,
                       filt, g);

    const long long total = (long long)in_sizes[0];
    const long long rows  = total / SCOPE;                 // 524288
    const int blocks      = (int)(rows / ROWS_PER_BLOCK);  // 8192, exact

    hipLaunchKernelGGL(circ_conv_kernel, dim3(blocks), dim3(BLOCK_THREADS), 0,
                       stream, activations, g, out);
}